// Round 1
// baseline (1704.460 us; speedup 1.0000x reference)
//
#include <hip/hip_runtime.h>
#include <cstdint>
#include <cstddef>

#define N_TOK 8192
#define DIM   2048
#define VOC   32000
#define BT    128            // token rows per block
#define BV    128            // vocab cols per block
#define BK    32             // K tile
#define NVT   (VOC / BV)     // 250 vocab tiles
#define NNT   (N_TOK / BT)   // 64 token tiles
#define KIT   (DIM / BK)     // 64 K iterations
#define IGNORE_IDX (-100)

typedef __attribute__((ext_vector_type(8))) short bf16x8;   // 8 bf16 in 4 VGPRs
typedef __attribute__((ext_vector_type(4))) float f32x4;    // MFMA 16x16 accumulator

// round-to-nearest-even fp32 -> bf16 (inputs are finite; no NaN handling needed)
__device__ __forceinline__ unsigned short f2b(float f) {
    unsigned int u = __float_as_uint(f);
    unsigned int r = (u + 0x7fffu + ((u >> 16) & 1u)) >> 16;
    return (unsigned short)r;
}

// ---------------------------------------------------------------------------
// Kernel 1: cast H and W to bf16 in workspace; zero the output accumulator.
// ---------------------------------------------------------------------------
__global__ void cast_zero_kernel(const float* __restrict__ H, const float* __restrict__ W,
                                 unsigned short* __restrict__ Hb, unsigned short* __restrict__ Wb,
                                 float* __restrict__ out)
{
    if (blockIdx.x == 0 && threadIdx.x == 0) out[0] = 0.0f;
    const size_t nh = (size_t)N_TOK * DIM / 4;
    const size_t nw = (size_t)VOC * DIM / 4;
    size_t t = (size_t)blockIdx.x * blockDim.x + threadIdx.x;
    size_t stride = (size_t)gridDim.x * blockDim.x;
    const float4* H4 = (const float4*)H;
    const float4* W4 = (const float4*)W;
    ushort4* Hb4 = (ushort4*)Hb;
    ushort4* Wb4 = (ushort4*)Wb;
    for (size_t i = t; i < nh; i += stride) {
        float4 v = H4[i];
        ushort4 o = { f2b(v.x), f2b(v.y), f2b(v.z), f2b(v.w) };
        Hb4[i] = o;
    }
    for (size_t i = t; i < nw; i += stride) {
        float4 v = W4[i];
        ushort4 o = { f2b(v.x), f2b(v.y), f2b(v.z), f2b(v.w) };
        Wb4[i] = o;
    }
}

// ---------------------------------------------------------------------------
// Kernel 2: 128x128 bf16 MFMA GEMM tile (logits = H · W^T) with fused
// per-row (max, sum-exp) epilogue + target-logit extraction.
// partMax/partSum layout: [NVT][N_TOK]  (coalesced for the reducer)
// ---------------------------------------------------------------------------
#define GLOAD_LDS(gptr, lptr) __builtin_amdgcn_global_load_lds(                     \
        (const __attribute__((address_space(1))) void*)(gptr),                      \
        (__attribute__((address_space(3))) void*)(lptr), 16, 0, 0)

__global__ __launch_bounds__(256, 3)
void lmhead_gemm(const unsigned short* __restrict__ Hb,
                 const unsigned short* __restrict__ Wb,
                 const int* __restrict__ labels,
                 float* __restrict__ partMax,
                 float* __restrict__ partSum,
                 float* __restrict__ tgt)
{
    __shared__ unsigned short ldsA[BT * BK];   // 8 KiB
    __shared__ unsigned short ldsB[BV * BK];   // 8 KiB
    __shared__ float pm[2][BT];
    __shared__ float ps[2][BT];
    __shared__ int   ltgt[BT];                 // label col local to this v-tile, or -1

    // supergroup-of-8 swizzle: 8 consecutive n-tiles share each W slice window
    int b = blockIdx.x;                        // 0 .. NNT*NVT-1 (16000)
    const int SG = 8;
    int group = b / (SG * NVT);
    int rem   = b % (SG * NVT);
    int vt    = rem / SG;
    int nt    = group * SG + (rem % SG);

    const int tid  = threadIdx.x;
    const int wave = tid >> 6;
    const int lane = tid & 63;
    const int wm   = wave >> 1;                // wave row (0..1) -> 64 token rows
    const int wn   = wave & 1;                 // wave col (0..1) -> 64 vocab cols
    const int l15  = lane & 15;
    const int q    = lane >> 4;

    const int rowBase = nt * BT;
    const int colBase = vt * BV;

    if (tid < BT) {
        int lb = labels[rowBase + tid];
        int lc = lb - colBase;
        ltgt[tid] = (lc >= 0 && lc < BV) ? lc : -1;
    }

    f32x4 acc[4][4];
#pragma unroll
    for (int i = 0; i < 4; ++i)
#pragma unroll
        for (int j = 0; j < 4; ++j)
            acc[i][j] = (f32x4){0.f, 0.f, 0.f, 0.f};

    // staging geometry: lane covers 8 contiguous bf16; 4 lanes per 32-elem row
    const int srow = lane >> 2;                // 0..15
    const int scol = (lane & 3) * 8;           // 0,8,16,24

    const unsigned short* gA = Hb + (size_t)rowBase * DIM;
    const unsigned short* gB = Wb + (size_t)colBase * DIM;

    for (int kt = 0; kt < KIT; ++kt) {
        const int k0 = kt * BK;
#pragma unroll
        for (int s = 0; s < 2; ++s) {
            int chunk = s * 4 + wave;          // wave-uniform, 0..7
            int row   = chunk * 16 + srow;     // 0..127
            GLOAD_LDS(gA + (size_t)row * DIM + k0 + scol, &ldsA[chunk * 16 * BK]);
            GLOAD_LDS(gB + (size_t)row * DIM + k0 + scol, &ldsB[chunk * 16 * BK]);
        }
        __syncthreads();   // compiler emits vmcnt(0) drain before barrier

        bf16x8 af[4], bf[4];
#pragma unroll
        for (int i = 0; i < 4; ++i)
            af[i] = *(const bf16x8*)&ldsA[(wm * 64 + i * 16 + l15) * BK + q * 8];
#pragma unroll
        for (int j = 0; j < 4; ++j)
            bf[j] = *(const bf16x8*)&ldsB[(wn * 64 + j * 16 + l15) * BK + q * 8];

#pragma unroll
        for (int i = 0; i < 4; ++i)
#pragma unroll
            for (int j = 0; j < 4; ++j)
                acc[i][j] = __builtin_amdgcn_mfma_f32_16x16x32_bf16(af[i], bf[j], acc[i][j], 0, 0, 0);

        __syncthreads();
    }

    // ---- fused epilogue: per-row max & sum(exp) over this block's 128 cols ----
    // C/D layout (16x16x32): col = lane&15, row = (lane>>4)*4 + reg
#pragma unroll
    for (int i = 0; i < 4; ++i) {
#pragma unroll
        for (int r = 0; r < 4; ++r) {
            float v0 = acc[i][0][r], v1 = acc[i][1][r], v2 = acc[i][2][r], v3 = acc[i][3][r];
            float mx = fmaxf(fmaxf(v0, v1), fmaxf(v2, v3));
            mx = fmaxf(mx, __shfl_xor(mx, 1));
            mx = fmaxf(mx, __shfl_xor(mx, 2));
            mx = fmaxf(mx, __shfl_xor(mx, 4));
            mx = fmaxf(mx, __shfl_xor(mx, 8));
            float s = __expf(v0 - mx) + __expf(v1 - mx) + __expf(v2 - mx) + __expf(v3 - mx);
            s += __shfl_xor(s, 1);
            s += __shfl_xor(s, 2);
            s += __shfl_xor(s, 4);
            s += __shfl_xor(s, 8);
            int localRow = wm * 64 + i * 16 + q * 4 + r;
            if (l15 == 0) { pm[wn][localRow] = mx; ps[wn][localRow] = s; }
            int tc = ltgt[localRow];
            if (tc >= 0) {
#pragma unroll
                for (int j = 0; j < 4; ++j) {
                    if (wn * 64 + j * 16 + l15 == tc)
                        tgt[rowBase + localRow] = acc[i][j][r];
                }
            }
        }
    }
    __syncthreads();

    if (tid < BT) {
        float m0 = pm[0][tid], m1 = pm[1][tid];
        float M = fmaxf(m0, m1);
        float S = ps[0][tid] * __expf(m0 - M) + ps[1][tid] * __expf(m1 - M);
        size_t o = (size_t)vt * N_TOK + rowBase + tid;
        partMax[o] = M;
        partSum[o] = S;
    }
}

// ---------------------------------------------------------------------------
// Kernel 3: per-row online logsumexp over 250 tile-partials, NLL, global sum.
// ---------------------------------------------------------------------------
__global__ void reduce_kernel(const float* __restrict__ partMax,
                              const float* __restrict__ partSum,
                              const float* __restrict__ tgt,
                              const int* __restrict__ labels,
                              float* __restrict__ out)
{
    __shared__ float red[4];
    const int tid = threadIdx.x;
    const int n = blockIdx.x * blockDim.x + tid;   // grid = N_TOK/256 blocks

    float M = -1e30f, S = 0.f;
    for (int t = 0; t < NVT; ++t) {
        float m = partMax[(size_t)t * N_TOK + n];  // coalesced
        float s = partSum[(size_t)t * N_TOK + n];
        float nM = fmaxf(M, m);
        S = S * __expf(M - nM) + s * __expf(m - nM);
        M = nM;
    }
    int lb = labels[n];
    float nll = 0.f;
    if (lb != IGNORE_IDX) nll = __logf(S) + M - tgt[n];

    // wave then block reduction
    float v = nll;
    v += __shfl_xor(v, 32);
    v += __shfl_xor(v, 16);
    v += __shfl_xor(v, 8);
    v += __shfl_xor(v, 4);
    v += __shfl_xor(v, 2);
    v += __shfl_xor(v, 1);
    if ((tid & 63) == 0) red[tid >> 6] = v;
    __syncthreads();
    if (tid == 0) atomicAdd(out, red[0] + red[1] + red[2] + red[3]);
}

// ---------------------------------------------------------------------------
extern "C" void kernel_launch(void* const* d_in, const int* in_sizes, int n_in,
                              void* d_out, int out_size, void* d_ws, size_t ws_size,
                              hipStream_t stream)
{
    const float* H      = (const float*)d_in[0];   // [8192, 2048] fp32
    const int*   labels = (const int*)d_in[1];     // [8192] int32
    const float* W      = (const float*)d_in[2];   // [32000, 2048] fp32
    float* out = (float*)d_out;                    // scalar loss

    // workspace layout
    char* ws = (char*)d_ws;
    size_t need = (size_t)VOC * DIM * 2 + (size_t)N_TOK * DIM * 2
                + 2 * (size_t)NVT * N_TOK * 4 + (size_t)N_TOK * 4;
    if (ws_size < need) return;   // fail loudly (validation) rather than corrupt

    unsigned short* Wb = (unsigned short*)ws;  ws += (size_t)VOC * DIM * 2;    // 131 MB
    unsigned short* Hb = (unsigned short*)ws;  ws += (size_t)N_TOK * DIM * 2;  // 33.5 MB
    float* partMax = (float*)ws;               ws += (size_t)NVT * N_TOK * 4;  // 8.2 MB
    float* partSum = (float*)ws;               ws += (size_t)NVT * N_TOK * 4;  // 8.2 MB
    float* tgt     = (float*)ws;                                               // 32 KB

    cast_zero_kernel<<<4096, 256, 0, stream>>>(H, W, Hb, Wb, out);
    lmhead_gemm<<<NNT * NVT, 256, 0, stream>>>(Hb, Wb, labels, partMax, partSum, tgt);
    reduce_kernel<<<N_TOK / 256, 256, 0, stream>>>(partMax, partSum, tgt, labels, out);
}